// Round 2
// baseline (983.144 us; speedup 1.0000x reference)
//
#include <hip/hip_runtime.h>
#include <cmath>

#define NPTS 4096
#define NB   8192      // B*N
#define DM   256
#define KK   48

// ---------------------------------------------------------------------------
// C1: Wk2 = Wk@Wpe2, Wv2 = Wv@Wpe2 (256x128 each); bkf = bk + Wk@bpe2, bvf likewise
__global__ __launch_bounds__(128) void prep_wkv2(
    const float* __restrict__ Win, const float* __restrict__ Wpe2,
    const float* __restrict__ bpe2, const float* __restrict__ bin_,
    float* __restrict__ Wk2, float* __restrict__ Wv2,
    float* __restrict__ bkf, float* __restrict__ bvf)
{
    const int o = blockIdx.x;          // 0..255 output row
    const int j = threadIdx.x;         // 0..127
    const float* wk = Win + (size_t)(256 + o) * 256;
    const float* wv = Win + (size_t)(512 + o) * 256;
    float ak = 0.f, av = 0.f;
    for (int d = 0; d < 256; ++d) {
        float pw = Wpe2[(size_t)d * 128 + j];
        ak = fmaf(wk[d], pw, ak);
        av = fmaf(wv[d], pw, av);
    }
    Wk2[(size_t)o * 128 + j] = ak;
    Wv2[(size_t)o * 128 + j] = av;

    __shared__ float pk[128], pv[128];
    pk[j] = wk[j] * bpe2[j] + wk[j + 128] * bpe2[j + 128];
    pv[j] = wv[j] * bpe2[j] + wv[j + 128] * bpe2[j + 128];
    __syncthreads();
    for (int off = 64; off >= 1; off >>= 1) {
        if (j < off) { pk[j] += pk[j + off]; pv[j] += pv[j + off]; }
        __syncthreads();
    }
    if (j == 0) {
        bkf[o] = bin_[256 + o] + pk[0];
        bvf[o] = bin_[512 + o] + pv[0];
    }
}

// ---------------------------------------------------------------------------
// C2: Wcat[o][0:256] = Wout row; Wcat[o][256 + h*128 + jj] = sum_{d'} Wout[o][64h+d'] * Wv2[64h+d'][jj]
__global__ __launch_bounds__(256) void prep_wcat(
    const float* __restrict__ Wout, const float* __restrict__ Wv2,
    float* __restrict__ Wcat)
{
    const int o = blockIdx.x;
    const int t = threadIdx.x;
    Wcat[(size_t)o * 768 + t] = Wout[(size_t)o * 256 + t];
    for (int v = t; v < 512; v += 256) {
        const int h = v >> 7, jj = v & 127;
        const float* wo  = Wout + (size_t)o * 256 + h * 64;
        const float* wv2 = Wv2 + (size_t)(h * 64) * 128 + jj;
        float a = 0.f;
        for (int dp = 0; dp < 64; ++dp) a = fmaf(wo[dp], wv2[(size_t)dp * 128], a);
        Wcat[(size_t)o * 768 + 256 + v] = a;
    }
}

// ---------------------------------------------------------------------------
// Generic row GEMM: Y[r][o] = (bias[o] + sum_d X[r][d] * W[o][d]) * scale
// 32 rows per block, 256 threads (thread = output column o).
__global__ __launch_bounds__(256) void rowgemm(
    const float* __restrict__ X, const float* __restrict__ W,
    const float* __restrict__ bias, float scale, float* __restrict__ Y)
{
    __shared__ __align__(16) float xs[32][256];
    const int tid = threadIdx.x;
    const int r0 = blockIdx.x * 32;
    for (int v = tid; v < 32 * 64; v += 256)
        ((float4*)xs)[v] = ((const float4*)(X + (size_t)r0 * 256))[v];
    __syncthreads();

    float acc[32];
    #pragma unroll
    for (int i = 0; i < 32; ++i) acc[i] = 0.f;
    const float* wr = W + (size_t)tid * 256;
    for (int d = 0; d < 256; d += 4) {
        float4 w4 = *(const float4*)(wr + d);
        #pragma unroll
        for (int i = 0; i < 32; ++i) {
            float4 x4 = *(const float4*)(&xs[i][d]);
            acc[i] = fmaf(w4.x, x4.x, fmaf(w4.y, x4.y, fmaf(w4.z, x4.z, fmaf(w4.w, x4.w, acc[i]))));
        }
    }
    const float bb = bias[tid];
    #pragma unroll
    for (int i = 0; i < 32; ++i)
        Y[(size_t)(r0 + i) * 256 + tid] = (acc[i] + bb) * scale;
}

// ---------------------------------------------------------------------------
// KNN: one block per query point. 16 candidates per thread in registers,
// 48 iterative block-argmin extractions (ascending distance, lower-index ties).
__global__ __launch_bounds__(256) void knn_kernel(
    const float* __restrict__ coords, int* __restrict__ nidx, float* __restrict__ ndist)
{
    #pragma clang fp contract(off)
    const int p = blockIdx.x;
    const int b = p >> 12;
    const int i = p & 4095;
    const int tid = threadIdx.x;
    const float* cb = coords + (size_t)b * NPTS * 3;
    const float xi = cb[i * 3 + 0], yi = cb[i * 3 + 1], ti = cb[i * 3 + 2];

    const float INF = INFINITY;
    float myd[16];
    #pragma unroll
    for (int s = 0; s < 16; ++s) {
        const int j = s * 256 + tid;
        const float xj = cb[j * 3 + 0], yj = cb[j * 3 + 1], tj = cb[j * 3 + 2];
        const float dx = xi - xj, dy = yi - yj;
        const float sd = sqrtf(dx * dx + dy * dy);
        const float dd = sd + 0.3f * fabsf(tj - ti);
        const bool bad = (j == i) || (tj > ti) || (sd > 50.0f);
        myd[s] = bad ? INF : dd;
    }
    float lmin = myd[0];
    int lslot = 0;
    #pragma unroll
    for (int s = 1; s < 16; ++s) if (myd[s] < lmin) { lmin = myd[s]; lslot = s; }

    __shared__ float wd[4];
    __shared__ unsigned wcs[4];
    const int lane = tid & 63, wid = tid >> 6;
    unsigned dead = 0u;

    for (int k = 0; k < KK; ++k) {
        float d = lmin;
        unsigned c = (unsigned)(lslot * 256 + tid);
        #pragma unroll
        for (int off = 1; off < 64; off <<= 1) {
            float d2 = __shfl_xor(d, off);
            unsigned c2 = (unsigned)__shfl_xor((int)c, off);
            if (d2 < d || (d2 == d && c2 < c)) { d = d2; c = c2; }
        }
        if (lane == 0) { wd[wid] = d; wcs[wid] = c; }
        __syncthreads();
        float bd = wd[0];
        unsigned bc_ = wcs[0];
        #pragma unroll
        for (int w = 1; w < 4; ++w) {
            float d2 = wd[w]; unsigned c2 = wcs[w];
            if (d2 < bd || (d2 == bd && c2 < bc_)) { bd = d2; bc_ = c2; }
        }
        if (tid == 0) {
            ndist[(size_t)p * KK + k] = bd;
            nidx[(size_t)p * KK + k] = (int)bc_;
        }
        if ((bc_ & 255u) == (unsigned)tid) {
            dead |= (1u << (bc_ >> 8));
            lmin = (dead & 1u) ? INF : myd[0];
            lslot = 0;
            #pragma unroll
            for (int s = 1; s < 16; ++s) {
                float v = ((dead >> s) & 1u) ? INF : myd[s];
                if (v < lmin) { lmin = v; lslot = s; }
            }
        }
        __syncthreads();
    }
}

// ---------------------------------------------------------------------------
// E1: qW[p][h*128+j] = sum_{d<64} Q[p][64h+d] * Wk2[64h+d][j]   (32 points/block)
__global__ __launch_bounds__(256) void qw_kernel(
    const float* __restrict__ Q, const float* __restrict__ Wk2, float* __restrict__ qWa)
{
    __shared__ __align__(16) float qsh[32][256];
    const int tid = threadIdx.x;
    const int p0 = blockIdx.x * 32;
    for (int v = tid; v < 32 * 64; v += 256)
        ((float4*)qsh)[v] = ((const float4*)(Q + (size_t)p0 * 256))[v];
    __syncthreads();

    const int j = tid & 127, hh = tid >> 7;
    float acc[2][32];
    #pragma unroll
    for (int a = 0; a < 2; ++a)
        #pragma unroll
        for (int pp = 0; pp < 32; ++pp) acc[a][pp] = 0.f;

    #pragma unroll
    for (int ih = 0; ih < 2; ++ih) {
        const int h = hh * 2 + ih;
        for (int d4 = 0; d4 < 16; ++d4) {
            const int dbase = h * 64 + d4 * 4;
            const float w0 = Wk2[(size_t)(dbase + 0) * 128 + j];
            const float w1 = Wk2[(size_t)(dbase + 1) * 128 + j];
            const float w2 = Wk2[(size_t)(dbase + 2) * 128 + j];
            const float w3 = Wk2[(size_t)(dbase + 3) * 128 + j];
            #pragma unroll
            for (int pp = 0; pp < 32; ++pp) {
                float4 q4 = *(const float4*)(&qsh[pp][dbase]);
                acc[ih][pp] = fmaf(w0, q4.x, fmaf(w1, q4.y, fmaf(w2, q4.z, fmaf(w3, q4.w, acc[ih][pp]))));
            }
        }
    }
    #pragma unroll
    for (int ih = 0; ih < 2; ++ih) {
        const int h = hh * 2 + ih;
        #pragma unroll
        for (int pp = 0; pp < 32; ++pp)
            qWa[(size_t)(p0 + pp) * 512 + h * 128 + j] = acc[ih][pp];
    }
}

// ---------------------------------------------------------------------------
// E2: per-point attention core + gate. Writes vh[p][0:256]=vbar_flat, [256:768]=hbar_flat,
// both already multiplied by ring gate weights; nonb flag for the no-neighbor case.
__global__ __launch_bounds__(256) void attn_kernel(
    const float* __restrict__ coords, const float* __restrict__ Q,
    const float* __restrict__ Kp, const float* __restrict__ Vp,
    const float* __restrict__ qWa,
    const int* __restrict__ nidx, const float* __restrict__ ndist,
    const float* __restrict__ Wpe1, const float* __restrict__ bpe1,
    const float* __restrict__ Wg1, const float* __restrict__ bg1,
    const float* __restrict__ Wg2, const float* __restrict__ bg2,
    float* __restrict__ vh, unsigned char* __restrict__ nonb)
{
    const int p = blockIdx.x;
    const int b = p >> 12;
    const int i = p & 4095;
    const int tid = threadIdx.x;

    __shared__ __align__(16) float qs[4][68];     // padded
    __shared__ __align__(16) float qw[4][132];    // padded
    __shared__ __align__(16) float rel[KK][4];
    __shared__ float kd[KK];
    __shared__ int   sidx[KK];
    __shared__ int   svalid[KK];
    __shared__ __align__(16) float hid[KK][132];  // padded
    __shared__ float wsh[KK][4];
    __shared__ float wring[4];

    // phase 0+1: loads
    for (int v = tid; v < 256; v += 256) qs[v >> 6][v & 63] = Q[(size_t)p * 256 + v];
    for (int v = tid; v < 512; v += 256) qw[v >> 7][v & 127] = qWa[(size_t)p * 512 + v];
    const float* cb = coords + (size_t)b * NPTS * 3;
    const float xi = cb[i * 3 + 0], yi = cb[i * 3 + 1], ti = cb[i * 3 + 2];
    if (tid < KK) {
        const float dd = ndist[(size_t)p * KK + tid];
        const int ix = nidx[(size_t)p * KK + tid];
        sidx[tid] = ix;
        const int val = (dd < 3.0e38f) ? 1 : 0;
        svalid[tid] = val;
        const float kdd = val ? dd : 0.f;
        kd[tid] = kdd;
        rel[tid][0] = cb[ix * 3 + 0] - xi;
        rel[tid][1] = cb[ix * 3 + 1] - yi;
        rel[tid][2] = cb[ix * 3 + 2] - ti;
        rel[tid][3] = kdd;
    }
    __syncthreads();

    // phase 2: wave 0 computes gate; all waves then compute hidden
    if (tid < 64) {
        const int val = (tid < KK) ? svalid[tid] : 0;
        float dtv = 0.f;
        if (tid < KK && val) dtv = fabsf(rel[tid][2]);
        const unsigned long long m = __ballot(val != 0);
        const int count = __popcll(m);
        const int vc = count > 0 ? count : 1;
        float sdt = dtv;
        #pragma unroll
        for (int off = 1; off < 64; off <<= 1) sdt += __shfl_xor(sdt, off);
        const float vcf = (float)vc;
        const float dtmean = sdt / vcf;
        float dq = 0.f;
        if (tid < KK && val) { float tq = dtv - dtmean; dq = tq * tq; }
        float sdq = dq;
        #pragma unroll
        for (int off = 1; off < 64; off <<= 1) sdq += __shfl_xor(sdq, off);
        const float dtstd = sqrtf(sdq / vcf + 1e-8f);
        const float dens = kd[vc - 1];
        const float g0 = fminf(fmaxf(dens / (dens + 1e-6f), 0.f), 10.f);
        const float g1v = fminf(fmaxf(vcf / 48.f, 0.f), 1.f);
        const float g2 = fminf(fmaxf(dtmean / (dtmean + 1e-6f), 0.f), 10.f);
        const float g3 = fminf(fmaxf(dtstd / (dtstd + 1e-6f), 0.f), 10.f);
        float gh = 0.f;
        if (tid < 32) {
            gh = bg1[tid] + g0 * Wg1[tid * 4 + 0] + g1v * Wg1[tid * 4 + 1]
               + g2 * Wg1[tid * 4 + 2] + g3 * Wg1[tid * 4 + 3];
            gh = fmaxf(gh, 0.f);
        }
        float gl[3];
        #pragma unroll
        for (int r = 0; r < 3; ++r) {
            float part = (tid < 32) ? gh * Wg2[r * 32 + tid] : 0.f;
            #pragma unroll
            for (int off = 1; off < 64; off <<= 1) part += __shfl_xor(part, off);
            gl[r] = part + bg2[r];
        }
        if (count < 1)  gl[0] = -INFINITY;
        if (count < 17) gl[1] = -INFINITY;
        if (count < 33) gl[2] = -INFINITY;
        float w0 = 0.f, w1 = 0.f, w2 = 0.f;
        if (count > 0) {
            const float mx = fmaxf(gl[0], fmaxf(gl[1], gl[2]));
            const float e0 = expf(gl[0] - mx), e1 = expf(gl[1] - mx), e2 = expf(gl[2] - mx);
            const float es = e0 + e1 + e2;
            w0 = e0 / es; w1 = e1 / es; w2 = e2 / es;
        }
        if (tid == 0) {
            wring[0] = w0; wring[1] = w1; wring[2] = w2;
            nonb[p] = (count == 0) ? (unsigned char)1 : (unsigned char)0;
        }
    }
    // hidden: 48x128, relu(Wpe1 @ rel + bpe1)
    for (int v = tid; v < KK * 128; v += 256) {
        const int s = v >> 7, jj = v & 127;
        const float4 r4 = *(const float4*)(&rel[s][0]);
        const float4 w4 = *(const float4*)(Wpe1 + (size_t)jj * 4);
        float hdd = bpe1[jj] + r4.x * w4.x + r4.y * w4.y + r4.z * w4.z + r4.w * w4.w;
        hid[s][jj] = fmaxf(hdd, 0.f);
    }
    __syncthreads();

    // phase 3: logits + per-ring softmax (wave r owns ring r)
    if (tid < 192) {
        const int s_ = tid >> 2, h_ = tid & 3;
        float acc = 0.f;
        const float4* hp = (const float4*)(&hid[s_][0]);
        const float4* qp = (const float4*)(&qw[h_][0]);
        #pragma unroll
        for (int j4 = 0; j4 < 32; ++j4) {
            float4 hv = hp[j4], qv = qp[j4];
            acc = fmaf(qv.x, hv.x, fmaf(qv.y, hv.y, fmaf(qv.z, hv.z, fmaf(qv.w, hv.w, acc))));
        }
        const float* kr = Kp + ((size_t)b * NPTS + sidx[s_]) * 256 + h_ * 64;
        const float4* qsp = (const float4*)(&qs[h_][0]);
        #pragma unroll
        for (int d4 = 0; d4 < 16; ++d4) {
            float4 kv = *(const float4*)(kr + d4 * 4);
            float4 qv = qsp[d4];
            acc = fmaf(qv.x, kv.x, fmaf(qv.y, kv.y, fmaf(qv.z, kv.z, fmaf(qv.w, kv.w, acc))));
        }
        float logit = svalid[s_] ? acc : -1e9f;
        float mx = logit;
        #pragma unroll
        for (int off = 4; off < 64; off <<= 1) mx = fmaxf(mx, __shfl_xor(mx, off));
        const float e = expf(logit - mx);
        float es = e;
        #pragma unroll
        for (int off = 4; off < 64; off <<= 1) es += __shfl_xor(es, off);
        wsh[s_][h_] = (e / es) * wring[tid >> 6];
    }
    __syncthreads();

    // phase 4: vbar -> vh[p][0:256]
    {
        const int h = tid >> 6, dp = tid & 63;
        const size_t bb = (size_t)b * NPTS;
        float acc = 0.f;
        for (int s = 0; s < KK; ++s) {
            const float wv = wsh[s][h];
            if (wv != 0.f)
                acc = fmaf(wv, Vp[(bb + sidx[s]) * 256 + h * 64 + dp], acc);
        }
        vh[(size_t)p * 768 + tid] = acc;
    }
    // phase 5: hbar -> vh[p][256:768]
    for (int v = tid; v < 512; v += 256) {
        const int h = v >> 7, jj = v & 127;
        float acc = 0.f;
        for (int s = 0; s < KK; ++s) acc = fmaf(wsh[s][h], hid[s][jj], acc);
        vh[(size_t)p * 768 + 256 + v] = acc;
    }
}

// ---------------------------------------------------------------------------
// E3: fused = [vbar|hbar] @ Wcat.T + bout(flag) + feat residual, then LayerNorm.
__global__ __launch_bounds__(256) void out_kernel(
    const float* __restrict__ vh, const float* __restrict__ Wcat,
    const float* __restrict__ bout, const float* __restrict__ feat,
    const float* __restrict__ gamma, const float* __restrict__ beta,
    const unsigned char* __restrict__ nonb, float* __restrict__ out)
{
    __shared__ __align__(16) float xs[16][768];
    __shared__ float xo[16][257];
    __shared__ float mu_s[16], rs_s[16];
    const int tid = threadIdx.x;
    const int p0 = blockIdx.x * 16;
    for (int v = tid; v < 16 * 192; v += 256)
        ((float4*)xs)[v] = ((const float4*)(vh + (size_t)p0 * 768))[v];
    __syncthreads();

    float acc[16];
    #pragma unroll
    for (int i = 0; i < 16; ++i) acc[i] = 0.f;
    const float* wr = Wcat + (size_t)tid * 768;
    for (int d = 0; d < 768; d += 4) {
        float4 w4 = *(const float4*)(wr + d);
        #pragma unroll
        for (int i = 0; i < 16; ++i) {
            float4 x4 = *(const float4*)(&xs[i][d]);
            acc[i] = fmaf(w4.x, x4.x, fmaf(w4.y, x4.y, fmaf(w4.z, x4.z, fmaf(w4.w, x4.w, acc[i]))));
        }
    }
    const float bo = bout[tid];
    #pragma unroll
    for (int i = 0; i < 16; ++i) {
        float x = acc[i] + (nonb[p0 + i] ? 0.f : bo) + feat[(size_t)(p0 + i) * 256 + tid];
        xo[i][tid] = x;
    }
    __syncthreads();
    const int team = tid >> 4, l16 = tid & 15;
    float s1 = 0.f, s2 = 0.f;
    for (int c = l16; c < 256; c += 16) { float x = xo[team][c]; s1 += x; s2 = fmaf(x, x, s2); }
    #pragma unroll
    for (int off = 8; off >= 1; off >>= 1) {
        s1 += __shfl_down(s1, off, 16);
        s2 += __shfl_down(s2, off, 16);
    }
    if (l16 == 0) {
        const float mu = s1 * (1.f / 256.f);
        const float var = s2 * (1.f / 256.f) - mu * mu;
        mu_s[team] = mu;
        rs_s[team] = 1.f / sqrtf(var + 1e-5f);
    }
    __syncthreads();
    #pragma unroll
    for (int i = 0; i < 16; ++i) {
        const float x = xo[i][tid];
        out[(size_t)(p0 + i) * 256 + tid] = (x - mu_s[i]) * rs_s[i] * gamma[tid] + beta[tid];
    }
}

// ---------------------------------------------------------------------------
extern "C" void kernel_launch(void* const* d_in, const int* in_sizes, int n_in,
                              void* d_out, int out_size, void* d_ws, size_t ws_size,
                              hipStream_t stream) {
    (void)in_sizes; (void)n_in; (void)out_size; (void)ws_size;
    const float* features = (const float*)d_in[0];
    const float* coords   = (const float*)d_in[1];
    const float* Wfeat    = (const float*)d_in[2];
    const float* bfeat    = (const float*)d_in[3];
    const float* Wpe1     = (const float*)d_in[4];
    const float* bpe1     = (const float*)d_in[5];
    const float* Wpe2     = (const float*)d_in[6];
    const float* bpe2     = (const float*)d_in[7];
    const float* Win      = (const float*)d_in[8];
    const float* bin_     = (const float*)d_in[9];
    const float* Wout     = (const float*)d_in[10];
    const float* bout     = (const float*)d_in[11];
    const float* Wg1      = (const float*)d_in[12];
    const float* bg1      = (const float*)d_in[13];
    const float* Wg2      = (const float*)d_in[14];
    const float* bg2      = (const float*)d_in[15];
    const float* gamma    = (const float*)d_in[16];
    const float* beta     = (const float*)d_in[17];
    float* out = (float*)d_out;

    // workspace layout (floats); total ~76 MB
    float* ws   = (float*)d_ws;
    float* feat = ws;
    float* Qm   = feat + (size_t)NB * DM;
    float* Kp   = Qm   + (size_t)NB * DM;
    float* Vp   = Kp   + (size_t)NB * DM;
    float* qWa  = Vp   + (size_t)NB * DM;
    float* vh   = qWa  + (size_t)NB * 512;
    float* Wk2  = vh   + (size_t)NB * 768;
    float* Wv2  = Wk2  + 256 * 128;
    float* Wcat = Wv2  + 256 * 128;
    float* bkf  = Wcat + 256 * 768;
    float* bvf  = bkf + 256;
    float* ndist = bvf + 256;
    int*   nidx = (int*)(ndist + (size_t)NB * KK);
    unsigned char* nonb = (unsigned char*)(nidx + (size_t)NB * KK);

    prep_wkv2<<<256, 128, 0, stream>>>(Win, Wpe2, bpe2, bin_, Wk2, Wv2, bkf, bvf);
    prep_wcat<<<256, 256, 0, stream>>>(Wout, Wv2, Wcat);

    rowgemm<<<NB / 32, 256, 0, stream>>>(features, Wfeat, bfeat, 1.0f, feat);
    rowgemm<<<NB / 32, 256, 0, stream>>>(feat, Win, bin_, 0.125f, Qm);
    rowgemm<<<NB / 32, 256, 0, stream>>>(feat, Win + 256 * 256, bkf, 1.0f, Kp);
    rowgemm<<<NB / 32, 256, 0, stream>>>(feat, Win + 512 * 256, bvf, 1.0f, Vp);

    knn_kernel<<<NB, 256, 0, stream>>>(coords, nidx, ndist);

    qw_kernel<<<NB / 32, 256, 0, stream>>>(Qm, Wk2, qWa);

    attn_kernel<<<NB, 256, 0, stream>>>(coords, Qm, Kp, Vp, qWa, nidx, ndist,
                                        Wpe1, bpe1, Wg1, bg1, Wg2, bg2, vh, nonb);

    out_kernel<<<NB / 16, 256, 0, stream>>>(vh, Wcat, bout, feat, gamma, beta, nonb, out);
}

// Round 4
// 841.786 us; speedup vs baseline: 1.1679x; 1.1679x over previous
//
#include <hip/hip_runtime.h>
#include <cmath>

#define NPTS 4096
#define NB   8192      // B*N
#define DM   256
#define KK   48

// ---------------------------------------------------------------------------
// C1: Wk2 = Wk@Wpe2, Wv2 = Wv@Wpe2 (256x128 each); bkf = bk + Wk@bpe2, bvf likewise
__global__ __launch_bounds__(128) void prep_wkv2(
    const float* __restrict__ Win, const float* __restrict__ Wpe2,
    const float* __restrict__ bpe2, const float* __restrict__ bin_,
    float* __restrict__ Wk2, float* __restrict__ Wv2,
    float* __restrict__ bkf, float* __restrict__ bvf)
{
    const int o = blockIdx.x;          // 0..255 output row
    const int j = threadIdx.x;         // 0..127
    const float* wk = Win + (size_t)(256 + o) * 256;
    const float* wv = Win + (size_t)(512 + o) * 256;
    float ak = 0.f, av = 0.f;
    for (int d = 0; d < 256; ++d) {
        float pw = Wpe2[(size_t)d * 128 + j];
        ak = fmaf(wk[d], pw, ak);
        av = fmaf(wv[d], pw, av);
    }
    Wk2[(size_t)o * 128 + j] = ak;
    Wv2[(size_t)o * 128 + j] = av;

    __shared__ float pk[128], pv[128];
    pk[j] = wk[j] * bpe2[j] + wk[j + 128] * bpe2[j + 128];
    pv[j] = wv[j] * bpe2[j] + wv[j + 128] * bpe2[j + 128];
    __syncthreads();
    for (int off = 64; off >= 1; off >>= 1) {
        if (j < off) { pk[j] += pk[j + off]; pv[j] += pv[j + off]; }
        __syncthreads();
    }
    if (j == 0) {
        bkf[o] = bin_[256 + o] + pk[0];
        bvf[o] = bin_[512 + o] + pv[0];
    }
}

// ---------------------------------------------------------------------------
// C2: Wcat[o][0:256] = Wout row; Wcat[o][256 + h*128 + jj] = sum_{d'} Wout[o][64h+d'] * Wv2[64h+d'][jj]
__global__ __launch_bounds__(256) void prep_wcat(
    const float* __restrict__ Wout, const float* __restrict__ Wv2,
    float* __restrict__ Wcat)
{
    const int o = blockIdx.x;
    const int t = threadIdx.x;
    Wcat[(size_t)o * 768 + t] = Wout[(size_t)o * 256 + t];
    for (int v = t; v < 512; v += 256) {
        const int h = v >> 7, jj = v & 127;
        const float* wo  = Wout + (size_t)o * 256 + h * 64;
        const float* wv2 = Wv2 + (size_t)(h * 64) * 128 + jj;
        float a = 0.f;
        for (int dp = 0; dp < 64; ++dp) a = fmaf(wo[dp], wv2[(size_t)dp * 128], a);
        Wcat[(size_t)o * 768 + 256 + v] = a;
    }
}

// ---------------------------------------------------------------------------
// Generic row GEMM: Y[r][o] = (bias[o] + sum_d X[r][d] * W[o][d]) * scale
// 32 rows per block, 256 threads (thread = output column o).
__global__ __launch_bounds__(256) void rowgemm(
    const float* __restrict__ X, const float* __restrict__ W,
    const float* __restrict__ bias, float scale, float* __restrict__ Y)
{
    __shared__ __align__(16) float xs[32][256];
    const int tid = threadIdx.x;
    const int r0 = blockIdx.x * 32;
    for (int v = tid; v < 32 * 64; v += 256)
        ((float4*)xs)[v] = ((const float4*)(X + (size_t)r0 * 256))[v];
    __syncthreads();

    float acc[32];
    #pragma unroll
    for (int i = 0; i < 32; ++i) acc[i] = 0.f;
    const float* wr = W + (size_t)tid * 256;
    for (int d = 0; d < 256; d += 4) {
        float4 w4 = *(const float4*)(wr + d);
        #pragma unroll
        for (int i = 0; i < 32; ++i) {
            float4 x4 = *(const float4*)(&xs[i][d]);
            acc[i] = fmaf(w4.x, x4.x, fmaf(w4.y, x4.y, fmaf(w4.z, x4.z, fmaf(w4.w, x4.w, acc[i]))));
        }
    }
    const float bb = bias[tid];
    #pragma unroll
    for (int i = 0; i < 32; ++i)
        Y[(size_t)(r0 + i) * 256 + tid] = (acc[i] + bb) * scale;
}

// ---------------------------------------------------------------------------
// KNN v2: one WAVE per point, 64 candidates per lane, no LDS / no barriers.
// 64-bit key = (distbits << 32) | candidate_index  — monotone for nonneg
// floats; ties break by lower index, exactly matching jax.lax.top_k.
// Lazy deletion via per-lane dead-mask + two-level tournament (4 group
// minima of 16, statically indexed so everything stays in VGPRs).

#define GRPMIN(BASE, OUTKEY) do {                                            \
    unsigned m_ = 0xFFFFFFFFu; int ms_ = (BASE);                             \
    _Pragma("unroll")                                                        \
    for (int s_ = 0; s_ < 16; ++s_) {                                        \
        unsigned v_ = ((dead >> ((BASE) + s_)) & 1ull) ? 0xFFFFFFFFu         \
                                                       : db[(BASE) + s_];    \
        if (v_ < m_) { m_ = v_; ms_ = (BASE) + s_; }                         \
    }                                                                        \
    OUTKEY = ((unsigned long long)m_ << 32) | (unsigned)(ms_ * 64 + lane);   \
} while (0)

static __device__ __forceinline__ unsigned long long umin64(
    unsigned long long a, unsigned long long b) { return a < b ? a : b; }

// 64-bit xor-shuffle via two 32-bit shuffles (defensive: guaranteed overloads)
static __device__ __forceinline__ unsigned long long shfl_xor_u64(
    unsigned long long v, int mask)
{
    unsigned lo = (unsigned)(v & 0xFFFFFFFFull);
    unsigned hi = (unsigned)(v >> 32);
    lo = (unsigned)__shfl_xor((int)lo, mask);
    hi = (unsigned)__shfl_xor((int)hi, mask);
    return ((unsigned long long)hi << 32) | lo;
}

__global__ __launch_bounds__(256) void knn_kernel(
    const float* __restrict__ coords, int* __restrict__ nidx, float* __restrict__ ndist)
{
    #pragma clang fp contract(off)
    const int lane = threadIdx.x & 63;
    const int p = blockIdx.x * 4 + (threadIdx.x >> 6);   // one wave per point
    const int b = p >> 12;
    const int i = p & 4095;
    const float* cb = coords + (size_t)b * NPTS * 3;
    const float xi = cb[i * 3 + 0], yi = cb[i * 3 + 1], ti = cb[i * 3 + 2];

    unsigned db[64];
    #pragma unroll
    for (int s = 0; s < 64; ++s) {
        const int j = s * 64 + lane;
        const float xj = cb[j * 3 + 0], yj = cb[j * 3 + 1], tj = cb[j * 3 + 2];
        const float dx = xi - xj, dy = yi - yj;
        const float sd = sqrtf(dx * dx + dy * dy);
        const float dd = sd + 0.3f * fabsf(tj - ti);
        const bool bad = (j == i) || (tj > ti) || (sd > 50.0f);
        db[s] = bad ? 0x7F800000u : __float_as_uint(dd);
    }

    unsigned long long dead = 0ull;
    unsigned long long k0, k1, k2, k3;
    GRPMIN(0,  k0); GRPMIN(16, k1); GRPMIN(32, k2); GRPMIN(48, k3);
    unsigned long long lmin = umin64(umin64(k0, k1), umin64(k2, k3));

    unsigned long long reskey = 0ull;
    for (int k = 0; k < KK; ++k) {
        unsigned long long kb = lmin;
        #pragma unroll
        for (int off = 1; off < 64; off <<= 1) {
            unsigned long long o = shfl_xor_u64(kb, off);
            kb = o < kb ? o : kb;
        }
        if (lane == k) reskey = kb;                     // lane k keeps result k
        const int wj = (int)(kb & 0xFFFFFFFFull);       // winning candidate idx
        if ((wj & 63) == lane) {                        // only owner lane rescans
            const int ws = wj >> 6;
            dead |= (1ull << ws);
            const int g = ws >> 4;
            if      (g == 0) GRPMIN(0,  k0);
            else if (g == 1) GRPMIN(16, k1);
            else if (g == 2) GRPMIN(32, k2);
            else             GRPMIN(48, k3);
            lmin = umin64(umin64(k0, k1), umin64(k2, k3));
        }
    }

    if (lane < KK) {
        ndist[(size_t)p * KK + lane] = __uint_as_float((unsigned)(reskey >> 32));
        nidx [(size_t)p * KK + lane] = (int)(reskey & 0xFFFFFFFFull);
    }
}

// ---------------------------------------------------------------------------
// E1: qW[p][h*128+j] = sum_{d<64} Q[p][64h+d] * Wk2[64h+d][j]   (32 points/block)
__global__ __launch_bounds__(256) void qw_kernel(
    const float* __restrict__ Q, const float* __restrict__ Wk2, float* __restrict__ qWa)
{
    __shared__ __align__(16) float qsh[32][256];
    const int tid = threadIdx.x;
    const int p0 = blockIdx.x * 32;
    for (int v = tid; v < 32 * 64; v += 256)
        ((float4*)qsh)[v] = ((const float4*)(Q + (size_t)p0 * 256))[v];
    __syncthreads();

    const int j = tid & 127, hh = tid >> 7;
    float acc[2][32];
    #pragma unroll
    for (int a = 0; a < 2; ++a)
        #pragma unroll
        for (int pp = 0; pp < 32; ++pp) acc[a][pp] = 0.f;

    #pragma unroll
    for (int ih = 0; ih < 2; ++ih) {
        const int h = hh * 2 + ih;
        for (int d4 = 0; d4 < 16; ++d4) {
            const int dbase = h * 64 + d4 * 4;
            const float w0 = Wk2[(size_t)(dbase + 0) * 128 + j];
            const float w1 = Wk2[(size_t)(dbase + 1) * 128 + j];
            const float w2 = Wk2[(size_t)(dbase + 2) * 128 + j];
            const float w3 = Wk2[(size_t)(dbase + 3) * 128 + j];
            #pragma unroll
            for (int pp = 0; pp < 32; ++pp) {
                float4 q4 = *(const float4*)(&qsh[pp][dbase]);
                acc[ih][pp] = fmaf(w0, q4.x, fmaf(w1, q4.y, fmaf(w2, q4.z, fmaf(w3, q4.w, acc[ih][pp]))));
            }
        }
    }
    #pragma unroll
    for (int ih = 0; ih < 2; ++ih) {
        const int h = hh * 2 + ih;
        #pragma unroll
        for (int pp = 0; pp < 32; ++pp)
            qWa[(size_t)(p0 + pp) * 512 + h * 128 + j] = acc[ih][pp];
    }
}

// ---------------------------------------------------------------------------
// E2: per-point attention core + gate. Writes vh[p][0:256]=vbar_flat, [256:768]=hbar_flat,
// both already multiplied by ring gate weights; nonb flag for the no-neighbor case.
__global__ __launch_bounds__(256) void attn_kernel(
    const float* __restrict__ coords, const float* __restrict__ Q,
    const float* __restrict__ Kp, const float* __restrict__ Vp,
    const float* __restrict__ qWa,
    const int* __restrict__ nidx, const float* __restrict__ ndist,
    const float* __restrict__ Wpe1, const float* __restrict__ bpe1,
    const float* __restrict__ Wg1, const float* __restrict__ bg1,
    const float* __restrict__ Wg2, const float* __restrict__ bg2,
    float* __restrict__ vh, unsigned char* __restrict__ nonb)
{
    const int p = blockIdx.x;
    const int b = p >> 12;
    const int i = p & 4095;
    const int tid = threadIdx.x;

    __shared__ __align__(16) float qs[4][68];     // padded
    __shared__ __align__(16) float qw[4][132];    // padded
    __shared__ __align__(16) float rel[KK][4];
    __shared__ float kd[KK];
    __shared__ int   sidx[KK];
    __shared__ int   svalid[KK];
    __shared__ __align__(16) float hid[KK][132];  // padded
    __shared__ float wsh[KK][4];
    __shared__ float wring[4];

    // phase 0+1: loads
    for (int v = tid; v < 256; v += 256) qs[v >> 6][v & 63] = Q[(size_t)p * 256 + v];
    for (int v = tid; v < 512; v += 256) qw[v >> 7][v & 127] = qWa[(size_t)p * 512 + v];
    const float* cb = coords + (size_t)b * NPTS * 3;
    const float xi = cb[i * 3 + 0], yi = cb[i * 3 + 1], ti = cb[i * 3 + 2];
    if (tid < KK) {
        const float dd = ndist[(size_t)p * KK + tid];
        const int ix = nidx[(size_t)p * KK + tid];
        sidx[tid] = ix;
        const int val = (dd < 3.0e38f) ? 1 : 0;
        svalid[tid] = val;
        const float kdd = val ? dd : 0.f;
        kd[tid] = kdd;
        rel[tid][0] = cb[ix * 3 + 0] - xi;
        rel[tid][1] = cb[ix * 3 + 1] - yi;
        rel[tid][2] = cb[ix * 3 + 2] - ti;
        rel[tid][3] = kdd;
    }
    __syncthreads();

    // phase 2: wave 0 computes gate; all waves then compute hidden
    if (tid < 64) {
        const int val = (tid < KK) ? svalid[tid] : 0;
        float dtv = 0.f;
        if (tid < KK && val) dtv = fabsf(rel[tid][2]);
        const unsigned long long m = __ballot(val != 0);
        const int count = __popcll(m);
        const int vc = count > 0 ? count : 1;
        float sdt = dtv;
        #pragma unroll
        for (int off = 1; off < 64; off <<= 1) sdt += __shfl_xor(sdt, off);
        const float vcf = (float)vc;
        const float dtmean = sdt / vcf;
        float dq = 0.f;
        if (tid < KK && val) { float tq = dtv - dtmean; dq = tq * tq; }
        float sdq = dq;
        #pragma unroll
        for (int off = 1; off < 64; off <<= 1) sdq += __shfl_xor(sdq, off);
        const float dtstd = sqrtf(sdq / vcf + 1e-8f);
        const float dens = kd[vc - 1];
        const float g0 = fminf(fmaxf(dens / (dens + 1e-6f), 0.f), 10.f);
        const float g1v = fminf(fmaxf(vcf / 48.f, 0.f), 1.f);
        const float g2 = fminf(fmaxf(dtmean / (dtmean + 1e-6f), 0.f), 10.f);
        const float g3 = fminf(fmaxf(dtstd / (dtstd + 1e-6f), 0.f), 10.f);
        float gh = 0.f;
        if (tid < 32) {
            gh = bg1[tid] + g0 * Wg1[tid * 4 + 0] + g1v * Wg1[tid * 4 + 1]
               + g2 * Wg1[tid * 4 + 2] + g3 * Wg1[tid * 4 + 3];
            gh = fmaxf(gh, 0.f);
        }
        float gl[3];
        #pragma unroll
        for (int r = 0; r < 3; ++r) {
            float part = (tid < 32) ? gh * Wg2[r * 32 + tid] : 0.f;
            #pragma unroll
            for (int off = 1; off < 64; off <<= 1) part += __shfl_xor(part, off);
            gl[r] = part + bg2[r];
        }
        if (count < 1)  gl[0] = -INFINITY;
        if (count < 17) gl[1] = -INFINITY;
        if (count < 33) gl[2] = -INFINITY;
        float w0 = 0.f, w1 = 0.f, w2 = 0.f;
        if (count > 0) {
            const float mx = fmaxf(gl[0], fmaxf(gl[1], gl[2]));
            const float e0 = expf(gl[0] - mx), e1 = expf(gl[1] - mx), e2 = expf(gl[2] - mx);
            const float es = e0 + e1 + e2;
            w0 = e0 / es; w1 = e1 / es; w2 = e2 / es;
        }
        if (tid == 0) {
            wring[0] = w0; wring[1] = w1; wring[2] = w2;
            nonb[p] = (count == 0) ? (unsigned char)1 : (unsigned char)0;
        }
    }
    // hidden: 48x128, relu(Wpe1 @ rel + bpe1)
    for (int v = tid; v < KK * 128; v += 256) {
        const int s = v >> 7, jj = v & 127;
        const float4 r4 = *(const float4*)(&rel[s][0]);
        const float4 w4 = *(const float4*)(Wpe1 + (size_t)jj * 4);
        float hdd = bpe1[jj] + r4.x * w4.x + r4.y * w4.y + r4.z * w4.z + r4.w * w4.w;
        hid[s][jj] = fmaxf(hdd, 0.f);
    }
    __syncthreads();

    // phase 3: logits + per-ring softmax (wave r owns ring r)
    if (tid < 192) {
        const int s_ = tid >> 2, h_ = tid & 3;
        float acc = 0.f;
        const float4* hp = (const float4*)(&hid[s_][0]);
        const float4* qp = (const float4*)(&qw[h_][0]);
        #pragma unroll
        for (int j4 = 0; j4 < 32; ++j4) {
            float4 hv = hp[j4], qv = qp[j4];
            acc = fmaf(qv.x, hv.x, fmaf(qv.y, hv.y, fmaf(qv.z, hv.z, fmaf(qv.w, hv.w, acc))));
        }
        const float* kr = Kp + ((size_t)b * NPTS + sidx[s_]) * 256 + h_ * 64;
        const float4* qsp = (const float4*)(&qs[h_][0]);
        #pragma unroll
        for (int d4 = 0; d4 < 16; ++d4) {
            float4 kv = *(const float4*)(kr + d4 * 4);
            float4 qv = qsp[d4];
            acc = fmaf(qv.x, kv.x, fmaf(qv.y, kv.y, fmaf(qv.z, kv.z, fmaf(qv.w, kv.w, acc))));
        }
        float logit = svalid[s_] ? acc : -1e9f;
        float mx = logit;
        #pragma unroll
        for (int off = 4; off < 64; off <<= 1) mx = fmaxf(mx, __shfl_xor(mx, off));
        const float e = expf(logit - mx);
        float es = e;
        #pragma unroll
        for (int off = 4; off < 64; off <<= 1) es += __shfl_xor(es, off);
        wsh[s_][h_] = (e / es) * wring[tid >> 6];
    }
    __syncthreads();

    // phase 4: vbar -> vh[p][0:256]
    {
        const int h = tid >> 6, dp = tid & 63;
        const size_t bb = (size_t)b * NPTS;
        float acc = 0.f;
        for (int s = 0; s < KK; ++s) {
            const float wv = wsh[s][h];
            if (wv != 0.f)
                acc = fmaf(wv, Vp[(bb + sidx[s]) * 256 + h * 64 + dp], acc);
        }
        vh[(size_t)p * 768 + tid] = acc;
    }
    // phase 5: hbar -> vh[p][256:768]
    for (int v = tid; v < 512; v += 256) {
        const int h = v >> 7, jj = v & 127;
        float acc = 0.f;
        for (int s = 0; s < KK; ++s) acc = fmaf(wsh[s][h], hid[s][jj], acc);
        vh[(size_t)p * 768 + 256 + v] = acc;
    }
}

// ---------------------------------------------------------------------------
// E3: fused = [vbar|hbar] @ Wcat.T + bout(flag) + feat residual, then LayerNorm.
__global__ __launch_bounds__(256) void out_kernel(
    const float* __restrict__ vh, const float* __restrict__ Wcat,
    const float* __restrict__ bout, const float* __restrict__ feat,
    const float* __restrict__ gamma, const float* __restrict__ beta,
    const unsigned char* __restrict__ nonb, float* __restrict__ out)
{
    __shared__ __align__(16) float xs[16][768];
    __shared__ float xo[16][257];
    __shared__ float mu_s[16], rs_s[16];
    const int tid = threadIdx.x;
    const int p0 = blockIdx.x * 16;
    for (int v = tid; v < 16 * 192; v += 256)
        ((float4*)xs)[v] = ((const float4*)(vh + (size_t)p0 * 768))[v];
    __syncthreads();

    float acc[16];
    #pragma unroll
    for (int i = 0; i < 16; ++i) acc[i] = 0.f;
    const float* wr = Wcat + (size_t)tid * 768;
    for (int d = 0; d < 768; d += 4) {
        float4 w4 = *(const float4*)(wr + d);
        #pragma unroll
        for (int i = 0; i < 16; ++i) {
            float4 x4 = *(const float4*)(&xs[i][d]);
            acc[i] = fmaf(w4.x, x4.x, fmaf(w4.y, x4.y, fmaf(w4.z, x4.z, fmaf(w4.w, x4.w, acc[i]))));
        }
    }
    const float bo = bout[tid];
    #pragma unroll
    for (int i = 0; i < 16; ++i) {
        float x = acc[i] + (nonb[p0 + i] ? 0.f : bo) + feat[(size_t)(p0 + i) * 256 + tid];
        xo[i][tid] = x;
    }
    __syncthreads();
    const int team = tid >> 4, l16 = tid & 15;
    float s1 = 0.f, s2 = 0.f;
    for (int c = l16; c < 256; c += 16) { float x = xo[team][c]; s1 += x; s2 = fmaf(x, x, s2); }
    #pragma unroll
    for (int off = 8; off >= 1; off >>= 1) {
        s1 += __shfl_down(s1, off, 16);
        s2 += __shfl_down(s2, off, 16);
    }
    if (l16 == 0) {
        const float mu = s1 * (1.f / 256.f);
        const float var = s2 * (1.f / 256.f) - mu * mu;
        mu_s[team] = mu;
        rs_s[team] = 1.f / sqrtf(var + 1e-5f);
    }
    __syncthreads();
    #pragma unroll
    for (int i = 0; i < 16; ++i) {
        const float x = xo[i][tid];
        out[(size_t)(p0 + i) * 256 + tid] = (x - mu_s[i]) * rs_s[i] * gamma[tid] + beta[tid];
    }
}

// ---------------------------------------------------------------------------
extern "C" void kernel_launch(void* const* d_in, const int* in_sizes, int n_in,
                              void* d_out, int out_size, void* d_ws, size_t ws_size,
                              hipStream_t stream) {
    (void)in_sizes; (void)n_in; (void)out_size; (void)ws_size;
    const float* features = (const float*)d_in[0];
    const float* coords   = (const float*)d_in[1];
    const float* Wfeat    = (const float*)d_in[2];
    const float* bfeat    = (const float*)d_in[3];
    const float* Wpe1     = (const float*)d_in[4];
    const float* bpe1     = (const float*)d_in[5];
    const float* Wpe2     = (const float*)d_in[6];
    const float* bpe2     = (const float*)d_in[7];
    const float* Win      = (const float*)d_in[8];
    const float* bin_     = (const float*)d_in[9];
    const float* Wout     = (const float*)d_in[10];
    const float* bout     = (const float*)d_in[11];
    const float* Wg1      = (const float*)d_in[12];
    const float* bg1      = (const float*)d_in[13];
    const float* Wg2      = (const float*)d_in[14];
    const float* bg2      = (const float*)d_in[15];
    const float* gamma    = (const float*)d_in[16];
    const float* beta     = (const float*)d_in[17];
    float* out = (float*)d_out;

    // workspace layout (floats); total ~76 MB
    float* ws   = (float*)d_ws;
    float* feat = ws;
    float* Qm   = feat + (size_t)NB * DM;
    float* Kp   = Qm   + (size_t)NB * DM;
    float* Vp   = Kp   + (size_t)NB * DM;
    float* qWa  = Vp   + (size_t)NB * DM;
    float* vh   = qWa  + (size_t)NB * 512;
    float* Wk2  = vh   + (size_t)NB * 768;
    float* Wv2  = Wk2  + 256 * 128;
    float* Wcat = Wv2  + 256 * 128;
    float* bkf  = Wcat + 256 * 768;
    float* bvf  = bkf + 256;
    float* ndist = bvf + 256;
    int*   nidx = (int*)(ndist + (size_t)NB * KK);
    unsigned char* nonb = (unsigned char*)(nidx + (size_t)NB * KK);

    prep_wkv2<<<256, 128, 0, stream>>>(Win, Wpe2, bpe2, bin_, Wk2, Wv2, bkf, bvf);
    prep_wcat<<<256, 256, 0, stream>>>(Wout, Wv2, Wcat);

    rowgemm<<<NB / 32, 256, 0, stream>>>(features, Wfeat, bfeat, 1.0f, feat);
    rowgemm<<<NB / 32, 256, 0, stream>>>(feat, Win, bin_, 0.125f, Qm);
    rowgemm<<<NB / 32, 256, 0, stream>>>(feat, Win + 256 * 256, bkf, 1.0f, Kp);
    rowgemm<<<NB / 32, 256, 0, stream>>>(feat, Win + 512 * 256, bvf, 1.0f, Vp);

    knn_kernel<<<NB / 4, 256, 0, stream>>>(coords, nidx, ndist);

    qw_kernel<<<NB / 32, 256, 0, stream>>>(Qm, Wk2, qWa);

    attn_kernel<<<NB, 256, 0, stream>>>(coords, Qm, Kp, Vp, qWa, nidx, ndist,
                                        Wpe1, bpe1, Wg1, bg1, Wg2, bg2, vh, nonb);

    out_kernel<<<NB / 16, 256, 0, stream>>>(vh, Wcat, bout, feat, gamma, beta, nonb, out);
}

// Round 5
// 606.380 us; speedup vs baseline: 1.6213x; 1.3882x over previous
//
#include <hip/hip_runtime.h>
#include <cmath>

#define NPTS 4096
#define NB   8192      // B*N
#define DM   256
#define KK   48

// ---------------------------------------------------------------------------
// C1: Wk2 = Wk@Wpe2, Wv2 = Wv@Wpe2 (256x128 each); bkf = bk + Wk@bpe2, bvf likewise
__global__ __launch_bounds__(128) void prep_wkv2(
    const float* __restrict__ Win, const float* __restrict__ Wpe2,
    const float* __restrict__ bpe2, const float* __restrict__ bin_,
    float* __restrict__ Wk2, float* __restrict__ Wv2,
    float* __restrict__ bkf, float* __restrict__ bvf)
{
    const int o = blockIdx.x;          // 0..255 output row
    const int j = threadIdx.x;         // 0..127
    const float* wk = Win + (size_t)(256 + o) * 256;
    const float* wv = Win + (size_t)(512 + o) * 256;
    float ak = 0.f, av = 0.f;
    for (int d = 0; d < 256; ++d) {
        float pw = Wpe2[(size_t)d * 128 + j];
        ak = fmaf(wk[d], pw, ak);
        av = fmaf(wv[d], pw, av);
    }
    Wk2[(size_t)o * 128 + j] = ak;
    Wv2[(size_t)o * 128 + j] = av;

    __shared__ float pk[128], pv[128];
    pk[j] = wk[j] * bpe2[j] + wk[j + 128] * bpe2[j + 128];
    pv[j] = wv[j] * bpe2[j] + wv[j + 128] * bpe2[j + 128];
    __syncthreads();
    for (int off = 64; off >= 1; off >>= 1) {
        if (j < off) { pk[j] += pk[j + off]; pv[j] += pv[j + off]; }
        __syncthreads();
    }
    if (j == 0) {
        bkf[o] = bin_[256 + o] + pk[0];
        bvf[o] = bin_[512 + o] + pv[0];
    }
}

// ---------------------------------------------------------------------------
// C1b: WqW2[o=h*128+j][d] = 0.125 * sum_{d'<64} Win[64h+d'][d] * Wk2[64h+d'][j]
//      bqW2[o]            = 0.125 * sum_{d'<64} bin_[64h+d']   * Wk2[64h+d'][j]
__global__ __launch_bounds__(256) void prep_wqw2(
    const float* __restrict__ Win, const float* __restrict__ Wk2,
    const float* __restrict__ bin_,
    float* __restrict__ WqW2, float* __restrict__ bqW2)
{
    const int o = blockIdx.x;          // 0..511
    const int h = o >> 7, j = o & 127;
    const int d = threadIdx.x;         // 0..255
    float acc = 0.f;
    for (int dp = 0; dp < 64; ++dp) {
        const float w2 = Wk2[(size_t)(64 * h + dp) * 128 + j];
        acc = fmaf(Win[(size_t)(64 * h + dp) * 256 + d], w2, acc);
    }
    WqW2[(size_t)o * 256 + d] = acc * 0.125f;
    if (d < 64) {
        float pb = bin_[64 * h + d] * Wk2[(size_t)(64 * h + d) * 128 + j];
        #pragma unroll
        for (int off = 1; off < 64; off <<= 1) pb += __shfl_xor(pb, off);
        if (d == 0) bqW2[o] = pb * 0.125f;
    }
}

// ---------------------------------------------------------------------------
// C2: Wcat[o][0:256] = Wout row; Wcat[o][256 + h*128 + jj] = sum_{d'} Wout[o][64h+d'] * Wv2[64h+d'][jj]
__global__ __launch_bounds__(256) void prep_wcat(
    const float* __restrict__ Wout, const float* __restrict__ Wv2,
    float* __restrict__ Wcat)
{
    const int o = blockIdx.x;
    const int t = threadIdx.x;
    Wcat[(size_t)o * 768 + t] = Wout[(size_t)o * 256 + t];
    for (int v = t; v < 512; v += 256) {
        const int h = v >> 7, jj = v & 127;
        const float* wo  = Wout + (size_t)o * 256 + h * 64;
        const float* wv2 = Wv2 + (size_t)(h * 64) * 128 + jj;
        float a = 0.f;
        for (int dp = 0; dp < 64; ++dp) a = fmaf(wo[dp], wv2[(size_t)dp * 128], a);
        Wcat[(size_t)o * 768 + 256 + v] = a;
    }
}

// ---------------------------------------------------------------------------
// Register-tiled fp32 GEMM core: 64x64 tile/block, BK=32, 4x4 acc/thread.
// Y[r][c] = (bias[c] + sum_k X[r][k] * W[c][k]) * scale
// LDS k-major with +1 pad; staging coalesced (32 consecutive k per lane).
#define GEMM_BODY(XPTR, XSTRIDE, WPTR, KDIM, R0, C0)                          \
    __shared__ float xs[32][65];                                              \
    __shared__ float wsd[32][65];                                             \
    const int tid = threadIdx.x;                                              \
    const int lm = tid >> 5, lk = tid & 31;                                   \
    const int rr = 4 * (tid & 15), cc = 4 * (tid >> 4);                       \
    float acc[4][4] = {{0.f,0.f,0.f,0.f},{0.f,0.f,0.f,0.f},                   \
                       {0.f,0.f,0.f,0.f},{0.f,0.f,0.f,0.f}};                  \
    for (int k0 = 0; k0 < (KDIM); k0 += 32) {                                 \
        __syncthreads();                                                      \
        _Pragma("unroll")                                                     \
        for (int it = 0; it < 8; ++it) {                                      \
            const int m = lm + it * 8;                                        \
            xs[lk][m]  = (XPTR)[(size_t)((R0) + m) * (XSTRIDE) + k0 + lk];    \
            wsd[lk][m] = (WPTR)[(size_t)((C0) + m) * (KDIM) + k0 + lk];       \
        }                                                                     \
        __syncthreads();                                                      \
        _Pragma("unroll")                                                     \
        for (int k = 0; k < 32; ++k) {                                        \
            const float4 xv = *(const float4*)&xs[k][rr];                     \
            const float4 wv = *(const float4*)&wsd[k][cc];                    \
            acc[0][0] = fmaf(xv.x, wv.x, acc[0][0]);                          \
            acc[0][1] = fmaf(xv.x, wv.y, acc[0][1]);                          \
            acc[0][2] = fmaf(xv.x, wv.z, acc[0][2]);                          \
            acc[0][3] = fmaf(xv.x, wv.w, acc[0][3]);                          \
            acc[1][0] = fmaf(xv.y, wv.x, acc[1][0]);                          \
            acc[1][1] = fmaf(xv.y, wv.y, acc[1][1]);                          \
            acc[1][2] = fmaf(xv.y, wv.z, acc[1][2]);                          \
            acc[1][3] = fmaf(xv.y, wv.w, acc[1][3]);                          \
            acc[2][0] = fmaf(xv.z, wv.x, acc[2][0]);                          \
            acc[2][1] = fmaf(xv.z, wv.y, acc[2][1]);                          \
            acc[2][2] = fmaf(xv.z, wv.z, acc[2][2]);                          \
            acc[2][3] = fmaf(xv.z, wv.w, acc[2][3]);                          \
            acc[3][0] = fmaf(xv.w, wv.x, acc[3][0]);                          \
            acc[3][1] = fmaf(xv.w, wv.y, acc[3][1]);                          \
            acc[3][2] = fmaf(xv.w, wv.z, acc[3][2]);                          \
            acc[3][3] = fmaf(xv.w, wv.w, acc[3][3]);                          \
        }                                                                     \
    }

__global__ __launch_bounds__(256) void gemm_plain(
    const float* __restrict__ X, int xstride,
    const float* __restrict__ W, const float* __restrict__ bias,
    float scale, float* __restrict__ Y, int ystride, int K, int ntiles)
{
    const int bid = blockIdx.x;
    const int r0 = (bid / ntiles) * 64;
    const int c0 = (bid % ntiles) * 64;
    GEMM_BODY(X, xstride, W, K, r0, c0)
    float b0 = 0.f, b1 = 0.f, b2 = 0.f, b3 = 0.f;
    if (bias) { b0 = bias[c0+cc+0]; b1 = bias[c0+cc+1]; b2 = bias[c0+cc+2]; b3 = bias[c0+cc+3]; }
    #pragma unroll
    for (int i = 0; i < 4; ++i) {
        float4 o;
        o.x = (acc[i][0] + b0) * scale;
        o.y = (acc[i][1] + b1) * scale;
        o.z = (acc[i][2] + b2) * scale;
        o.w = (acc[i][3] + b3) * scale;
        *(float4*)&Y[(size_t)(r0 + rr + i) * ystride + c0 + cc] = o;
    }
}

// Fused QKV+qW GEMM: X=feat (8192x256), virtual N=1280 in 4 segments.
// seg0 cols   0- 255: Qm  = (feat@Wq^T  + bin_ )*0.125, stride 256
// seg1 cols 256- 511: Kp  =  feat@Wk^T  + bkf,          stride 256
// seg2 cols 512- 767: Vp  =  feat@Wv^T  + bvf,          stride 256
// seg3 cols 768-1279: qWa =  feat@WqW2^T+ bqW2,         stride 512
__global__ __launch_bounds__(256) void gemm_qkvw(
    const float* __restrict__ feat, const float* __restrict__ Win,
    const float* __restrict__ WqW2,
    const float* __restrict__ bin_, const float* __restrict__ bkf,
    const float* __restrict__ bvf, const float* __restrict__ bqW2,
    float* __restrict__ Qm, float* __restrict__ Kp,
    float* __restrict__ Vp, float* __restrict__ qWa)
{
    const int bid = blockIdx.x;
    const int r0 = (bid / 20) * 64;
    const int cg = (bid % 20) * 64;       // global col
    const float* Wb; const float* bb; float scale; float* Yb; int ys; int c0;
    if (cg < 256)      { Wb = Win;             bb = bin_; scale = 0.125f; Yb = Qm;  ys = 256; c0 = cg; }
    else if (cg < 512) { Wb = Win + 256 * 256; bb = bkf;  scale = 1.f;    Yb = Kp;  ys = 256; c0 = cg - 256; }
    else if (cg < 768) { Wb = Win + 512 * 256; bb = bvf;  scale = 1.f;    Yb = Vp;  ys = 256; c0 = cg - 512; }
    else               { Wb = WqW2;            bb = bqW2; scale = 1.f;    Yb = qWa; ys = 512; c0 = cg - 768; }
    GEMM_BODY(feat, 256, Wb, 256, r0, c0)
    const float b0 = bb[c0+cc+0], b1 = bb[c0+cc+1], b2 = bb[c0+cc+2], b3 = bb[c0+cc+3];
    #pragma unroll
    for (int i = 0; i < 4; ++i) {
        float4 o;
        o.x = (acc[i][0] + b0) * scale;
        o.y = (acc[i][1] + b1) * scale;
        o.z = (acc[i][2] + b2) * scale;
        o.w = (acc[i][3] + b3) * scale;
        *(float4*)&Yb[(size_t)(r0 + rr + i) * ys + c0 + cc] = o;
    }
}

// ---------------------------------------------------------------------------
// KNN v2: one WAVE per point, 64 candidates per lane, no LDS / no barriers.
#define GRPMIN(BASE, OUTKEY) do {                                            \
    unsigned m_ = 0xFFFFFFFFu; int ms_ = (BASE);                             \
    _Pragma("unroll")                                                        \
    for (int s_ = 0; s_ < 16; ++s_) {                                        \
        unsigned v_ = ((dead >> ((BASE) + s_)) & 1ull) ? 0xFFFFFFFFu         \
                                                       : db[(BASE) + s_];    \
        if (v_ < m_) { m_ = v_; ms_ = (BASE) + s_; }                         \
    }                                                                        \
    OUTKEY = ((unsigned long long)m_ << 32) | (unsigned)(ms_ * 64 + lane);   \
} while (0)

static __device__ __forceinline__ unsigned long long umin64(
    unsigned long long a, unsigned long long b) { return a < b ? a : b; }

static __device__ __forceinline__ unsigned long long shfl_xor_u64(
    unsigned long long v, int mask)
{
    unsigned lo = (unsigned)(v & 0xFFFFFFFFull);
    unsigned hi = (unsigned)(v >> 32);
    lo = (unsigned)__shfl_xor((int)lo, mask);
    hi = (unsigned)__shfl_xor((int)hi, mask);
    return ((unsigned long long)hi << 32) | lo;
}

__global__ __launch_bounds__(256) void knn_kernel(
    const float* __restrict__ coords, int* __restrict__ nidx, float* __restrict__ ndist)
{
    #pragma clang fp contract(off)
    const int lane = threadIdx.x & 63;
    const int p = blockIdx.x * 4 + (threadIdx.x >> 6);   // one wave per point
    const int b = p >> 12;
    const int i = p & 4095;
    const float* cb = coords + (size_t)b * NPTS * 3;
    const float xi = cb[i * 3 + 0], yi = cb[i * 3 + 1], ti = cb[i * 3 + 2];

    unsigned db[64];
    #pragma unroll
    for (int s = 0; s < 64; ++s) {
        const int j = s * 64 + lane;
        const float xj = cb[j * 3 + 0], yj = cb[j * 3 + 1], tj = cb[j * 3 + 2];
        const float dx = xi - xj, dy = yi - yj;
        const float sd = sqrtf(dx * dx + dy * dy);
        const float dd = sd + 0.3f * fabsf(tj - ti);
        const bool bad = (j == i) || (tj > ti) || (sd > 50.0f);
        db[s] = bad ? 0x7F800000u : __float_as_uint(dd);
    }

    unsigned long long dead = 0ull;
    unsigned long long k0, k1, k2, k3;
    GRPMIN(0,  k0); GRPMIN(16, k1); GRPMIN(32, k2); GRPMIN(48, k3);
    unsigned long long lmin = umin64(umin64(k0, k1), umin64(k2, k3));

    unsigned long long reskey = 0ull;
    for (int k = 0; k < KK; ++k) {
        unsigned long long kb = lmin;
        #pragma unroll
        for (int off = 1; off < 64; off <<= 1) {
            unsigned long long o = shfl_xor_u64(kb, off);
            kb = o < kb ? o : kb;
        }
        if (lane == k) reskey = kb;                     // lane k keeps result k
        const int wj = (int)(kb & 0xFFFFFFFFull);       // winning candidate idx
        if ((wj & 63) == lane) {                        // only owner lane rescans
            const int ws = wj >> 6;
            dead |= (1ull << ws);
            const int g = ws >> 4;
            if      (g == 0) GRPMIN(0,  k0);
            else if (g == 1) GRPMIN(16, k1);
            else if (g == 2) GRPMIN(32, k2);
            else             GRPMIN(48, k3);
            lmin = umin64(umin64(k0, k1), umin64(k2, k3));
        }
    }

    if (lane < KK) {
        ndist[(size_t)p * KK + lane] = __uint_as_float((unsigned)(reskey >> 32));
        nidx [(size_t)p * KK + lane] = (int)(reskey & 0xFFFFFFFFull);
    }
}

// ---------------------------------------------------------------------------
// E2: per-point attention core + gate. Writes vh[p][0:256]=vbar_flat, [256:768]=hbar_flat,
// both already multiplied by ring gate weights; nonb flag for the no-neighbor case.
__global__ __launch_bounds__(256) void attn_kernel(
    const float* __restrict__ coords, const float* __restrict__ Q,
    const float* __restrict__ Kp, const float* __restrict__ Vp,
    const float* __restrict__ qWa,
    const int* __restrict__ nidx, const float* __restrict__ ndist,
    const float* __restrict__ Wpe1, const float* __restrict__ bpe1,
    const float* __restrict__ Wg1, const float* __restrict__ bg1,
    const float* __restrict__ Wg2, const float* __restrict__ bg2,
    float* __restrict__ vh, unsigned char* __restrict__ nonb)
{
    const int p = blockIdx.x;
    const int b = p >> 12;
    const int i = p & 4095;
    const int tid = threadIdx.x;

    __shared__ __align__(16) float qs[4][68];     // padded
    __shared__ __align__(16) float qw[4][132];    // padded
    __shared__ __align__(16) float rel[KK][4];
    __shared__ float kd[KK];
    __shared__ int   sidx[KK];
    __shared__ int   svalid[KK];
    __shared__ __align__(16) float hid[KK][132];  // padded
    __shared__ float wsh[KK][4];
    __shared__ float wring[4];

    // phase 0+1: loads
    for (int v = tid; v < 256; v += 256) qs[v >> 6][v & 63] = Q[(size_t)p * 256 + v];
    for (int v = tid; v < 512; v += 256) qw[v >> 7][v & 127] = qWa[(size_t)p * 512 + v];
    const float* cb = coords + (size_t)b * NPTS * 3;
    const float xi = cb[i * 3 + 0], yi = cb[i * 3 + 1], ti = cb[i * 3 + 2];
    if (tid < KK) {
        const float dd = ndist[(size_t)p * KK + tid];
        const int ix = nidx[(size_t)p * KK + tid];
        sidx[tid] = ix;
        const int val = (dd < 3.0e38f) ? 1 : 0;
        svalid[tid] = val;
        const float kdd = val ? dd : 0.f;
        kd[tid] = kdd;
        rel[tid][0] = cb[ix * 3 + 0] - xi;
        rel[tid][1] = cb[ix * 3 + 1] - yi;
        rel[tid][2] = cb[ix * 3 + 2] - ti;
        rel[tid][3] = kdd;
    }
    __syncthreads();

    // phase 2: wave 0 computes gate; all waves then compute hidden
    if (tid < 64) {
        const int val = (tid < KK) ? svalid[tid] : 0;
        float dtv = 0.f;
        if (tid < KK && val) dtv = fabsf(rel[tid][2]);
        const unsigned long long m = __ballot(val != 0);
        const int count = __popcll(m);
        const int vc = count > 0 ? count : 1;
        float sdt = dtv;
        #pragma unroll
        for (int off = 1; off < 64; off <<= 1) sdt += __shfl_xor(sdt, off);
        const float vcf = (float)vc;
        const float dtmean = sdt / vcf;
        float dq = 0.f;
        if (tid < KK && val) { float tq = dtv - dtmean; dq = tq * tq; }
        float sdq = dq;
        #pragma unroll
        for (int off = 1; off < 64; off <<= 1) sdq += __shfl_xor(sdq, off);
        const float dtstd = sqrtf(sdq / vcf + 1e-8f);
        const float dens = kd[vc - 1];
        const float g0 = fminf(fmaxf(dens / (dens + 1e-6f), 0.f), 10.f);
        const float g1v = fminf(fmaxf(vcf / 48.f, 0.f), 1.f);
        const float g2 = fminf(fmaxf(dtmean / (dtmean + 1e-6f), 0.f), 10.f);
        const float g3 = fminf(fmaxf(dtstd / (dtstd + 1e-6f), 0.f), 10.f);
        float gh = 0.f;
        if (tid < 32) {
            gh = bg1[tid] + g0 * Wg1[tid * 4 + 0] + g1v * Wg1[tid * 4 + 1]
               + g2 * Wg1[tid * 4 + 2] + g3 * Wg1[tid * 4 + 3];
            gh = fmaxf(gh, 0.f);
        }
        float gl[3];
        #pragma unroll
        for (int r = 0; r < 3; ++r) {
            float part = (tid < 32) ? gh * Wg2[r * 32 + tid] : 0.f;
            #pragma unroll
            for (int off = 1; off < 64; off <<= 1) part += __shfl_xor(part, off);
            gl[r] = part + bg2[r];
        }
        if (count < 1)  gl[0] = -INFINITY;
        if (count < 17) gl[1] = -INFINITY;
        if (count < 33) gl[2] = -INFINITY;
        float w0 = 0.f, w1 = 0.f, w2 = 0.f;
        if (count > 0) {
            const float mx = fmaxf(gl[0], fmaxf(gl[1], gl[2]));
            const float e0 = expf(gl[0] - mx), e1 = expf(gl[1] - mx), e2 = expf(gl[2] - mx);
            const float es = e0 + e1 + e2;
            w0 = e0 / es; w1 = e1 / es; w2 = e2 / es;
        }
        if (tid == 0) {
            wring[0] = w0; wring[1] = w1; wring[2] = w2;
            nonb[p] = (count == 0) ? (unsigned char)1 : (unsigned char)0;
        }
    }
    // hidden: 48x128, relu(Wpe1 @ rel + bpe1)
    for (int v = tid; v < KK * 128; v += 256) {
        const int s = v >> 7, jj = v & 127;
        const float4 r4 = *(const float4*)(&rel[s][0]);
        const float4 w4 = *(const float4*)(Wpe1 + (size_t)jj * 4);
        float hdd = bpe1[jj] + r4.x * w4.x + r4.y * w4.y + r4.z * w4.z + r4.w * w4.w;
        hid[s][jj] = fmaxf(hdd, 0.f);
    }
    __syncthreads();

    // phase 3: logits + per-ring softmax (wave r owns ring r)
    if (tid < 192) {
        const int s_ = tid >> 2, h_ = tid & 3;
        float acc = 0.f;
        const float4* hp = (const float4*)(&hid[s_][0]);
        const float4* qp = (const float4*)(&qw[h_][0]);
        #pragma unroll
        for (int j4 = 0; j4 < 32; ++j4) {
            float4 hv = hp[j4], qv = qp[j4];
            acc = fmaf(qv.x, hv.x, fmaf(qv.y, hv.y, fmaf(qv.z, hv.z, fmaf(qv.w, hv.w, acc))));
        }
        const float* kr = Kp + ((size_t)b * NPTS + sidx[s_]) * 256 + h_ * 64;
        const float4* qsp = (const float4*)(&qs[h_][0]);
        #pragma unroll
        for (int d4 = 0; d4 < 16; ++d4) {
            float4 kv = *(const float4*)(kr + d4 * 4);
            float4 qv = qsp[d4];
            acc = fmaf(qv.x, kv.x, fmaf(qv.y, kv.y, fmaf(qv.z, kv.z, fmaf(qv.w, kv.w, acc))));
        }
        float logit = svalid[s_] ? acc : -1e9f;
        float mx = logit;
        #pragma unroll
        for (int off = 4; off < 64; off <<= 1) mx = fmaxf(mx, __shfl_xor(mx, off));
        const float e = expf(logit - mx);
        float es = e;
        #pragma unroll
        for (int off = 4; off < 64; off <<= 1) es += __shfl_xor(es, off);
        wsh[s_][h_] = (e / es) * wring[tid >> 6];
    }
    __syncthreads();

    // phase 4: vbar -> vh[p][0:256]  (4 independent gather chains for ILP)
    {
        const int h = tid >> 6, dp = tid & 63;
        const size_t bb = (size_t)b * NPTS;
        const float* vpb = Vp + h * 64 + dp;
        float a0 = 0.f, a1 = 0.f, a2 = 0.f, a3 = 0.f;
        #pragma unroll
        for (int s = 0; s < 12; ++s) {
            a0 = fmaf(wsh[s     ][h], vpb[(bb + sidx[s     ]) * 256], a0);
            a1 = fmaf(wsh[s + 12][h], vpb[(bb + sidx[s + 12]) * 256], a1);
            a2 = fmaf(wsh[s + 24][h], vpb[(bb + sidx[s + 24]) * 256], a2);
            a3 = fmaf(wsh[s + 36][h], vpb[(bb + sidx[s + 36]) * 256], a3);
        }
        vh[(size_t)p * 768 + tid] = (a0 + a1) + (a2 + a3);
    }
    // phase 5: hbar -> vh[p][256:768]  (2 chains)
    for (int v = tid; v < 512; v += 256) {
        const int h = v >> 7, jj = v & 127;
        float a0 = 0.f, a1 = 0.f;
        #pragma unroll
        for (int s = 0; s < 24; ++s) {
            a0 = fmaf(wsh[s     ][h], hid[s     ][jj], a0);
            a1 = fmaf(wsh[s + 24][h], hid[s + 24][jj], a1);
        }
        vh[(size_t)p * 768 + 256 + v] = a0 + a1;
    }
}

// ---------------------------------------------------------------------------
// E3b: LayerNorm epilogue: x = xo + (nonb?0:bout) + feat; LN; out.
// One wave per row, 4 rows per block.
__global__ __launch_bounds__(256) void ln_kernel(
    const float* __restrict__ xo, const float* __restrict__ feat,
    const float* __restrict__ bout, const unsigned char* __restrict__ nonb,
    const float* __restrict__ gamma, const float* __restrict__ beta,
    float* __restrict__ out)
{
    const int lane = threadIdx.x & 63;
    const int p = blockIdx.x * 4 + (threadIdx.x >> 6);
    const float4 xv = *(const float4*)&xo  [(size_t)p * 256 + lane * 4];
    const float4 fv = *(const float4*)&feat[(size_t)p * 256 + lane * 4];
    const float4 bv = *(const float4*)&bout[lane * 4];
    const float bm = nonb[p] ? 0.f : 1.f;
    float x0 = xv.x + fv.x + bm * bv.x;
    float x1 = xv.y + fv.y + bm * bv.y;
    float x2 = xv.z + fv.z + bm * bv.z;
    float x3 = xv.w + fv.w + bm * bv.w;
    float s1 = x0 + x1 + x2 + x3;
    float s2 = fmaf(x0, x0, fmaf(x1, x1, fmaf(x2, x2, x3 * x3)));
    #pragma unroll
    for (int off = 1; off < 64; off <<= 1) {
        s1 += __shfl_xor(s1, off);
        s2 += __shfl_xor(s2, off);
    }
    const float mu = s1 * (1.f / 256.f);
    const float var = s2 * (1.f / 256.f) - mu * mu;
    const float rs = 1.f / sqrtf(var + 1e-5f);
    const float4 gv = *(const float4*)&gamma[lane * 4];
    const float4 tv = *(const float4*)&beta [lane * 4];
    float4 o;
    o.x = (x0 - mu) * rs * gv.x + tv.x;
    o.y = (x1 - mu) * rs * gv.y + tv.y;
    o.z = (x2 - mu) * rs * gv.z + tv.z;
    o.w = (x3 - mu) * rs * gv.w + tv.w;
    *(float4*)&out[(size_t)p * 256 + lane * 4] = o;
}

// ---------------------------------------------------------------------------
extern "C" void kernel_launch(void* const* d_in, const int* in_sizes, int n_in,
                              void* d_out, int out_size, void* d_ws, size_t ws_size,
                              hipStream_t stream) {
    (void)in_sizes; (void)n_in; (void)out_size; (void)ws_size;
    const float* features = (const float*)d_in[0];
    const float* coords   = (const float*)d_in[1];
    const float* Wfeat    = (const float*)d_in[2];
    const float* bfeat    = (const float*)d_in[3];
    const float* Wpe1     = (const float*)d_in[4];
    const float* bpe1     = (const float*)d_in[5];
    const float* Wpe2     = (const float*)d_in[6];
    const float* bpe2     = (const float*)d_in[7];
    const float* Win      = (const float*)d_in[8];
    const float* bin_     = (const float*)d_in[9];
    const float* Wout     = (const float*)d_in[10];
    const float* bout     = (const float*)d_in[11];
    const float* Wg1      = (const float*)d_in[12];
    const float* bg1      = (const float*)d_in[13];
    const float* Wg2      = (const float*)d_in[14];
    const float* bg2      = (const float*)d_in[15];
    const float* gamma    = (const float*)d_in[16];
    const float* beta     = (const float*)d_in[17];
    float* out = (float*)d_out;

    // workspace layout (floats); ~76 MB (xo aliases Qm — dead after attn)
    float* ws   = (float*)d_ws;
    float* feat = ws;
    float* Qm   = feat + (size_t)NB * DM;
    float* Kp   = Qm   + (size_t)NB * DM;
    float* Vp   = Kp   + (size_t)NB * DM;
    float* qWa  = Vp   + (size_t)NB * DM;
    float* vh   = qWa  + (size_t)NB * 512;
    float* Wk2  = vh   + (size_t)NB * 768;
    float* Wv2  = Wk2  + 256 * 128;
    float* Wcat = Wv2  + 256 * 128;
    float* WqW2 = Wcat + 256 * 768;
    float* bkf  = WqW2 + 512 * 256;
    float* bvf  = bkf + 256;
    float* bqW2 = bvf + 256;
    float* ndist = bqW2 + 512;
    int*   nidx = (int*)(ndist + (size_t)NB * KK);
    unsigned char* nonb = (unsigned char*)(nidx + (size_t)NB * KK);
    float* xo   = Qm;   // alias: Qm dead after attn_kernel

    prep_wkv2<<<256, 128, 0, stream>>>(Win, Wpe2, bpe2, bin_, Wk2, Wv2, bkf, bvf);
    prep_wqw2<<<512, 256, 0, stream>>>(Win, Wk2, bin_, WqW2, bqW2);
    prep_wcat<<<256, 256, 0, stream>>>(Wout, Wv2, Wcat);

    // feat = features @ Wfeat^T + bfeat
    gemm_plain<<<(NB / 64) * 4, 256, 0, stream>>>(
        features, 256, Wfeat, bfeat, 1.0f, feat, 256, 256, 4);

    // fused Q/K/V/qW
    gemm_qkvw<<<(NB / 64) * 20, 256, 0, stream>>>(
        feat, Win, WqW2, bin_, bkf, bvf, bqW2, Qm, Kp, Vp, qWa);

    knn_kernel<<<NB / 4, 256, 0, stream>>>(coords, nidx, ndist);

    attn_kernel<<<NB, 256, 0, stream>>>(coords, Qm, Kp, Vp, qWa, nidx, ndist,
                                        Wpe1, bpe1, Wg1, bg1, Wg2, bg2, vh, nonb);

    // xo = vh @ Wcat^T   (bias/residual/LN handled by ln_kernel)
    gemm_plain<<<(NB / 64) * 4, 256, 0, stream>>>(
        vh, 768, Wcat, nullptr, 1.0f, xo, 256, 768, 4);

    ln_kernel<<<NB / 4, 256, 0, stream>>>(xo, feat, bout, nonb, gamma, beta, out);
}